// Round 12
// baseline (127.831 us; speedup 1.0000x reference)
//
#include <hip/hip_runtime.h>

#define EPS 1e-5f

typedef float v2f __attribute__((ext_vector_type(2)));

constexpr int B = 32;
constexpr int H = 512;
constexpr int W = 512;
constexpr int NPIX = H * W;          // 262144
constexpr int P = 13;
constexpr int HP = H - P + 1;        // 500
constexpr int WP = W - P + 1;        // 500
constexpr int TILE_W = 128;          // output cols per wave, 2 per lane
constexpr int TILES_X = 4;
constexpr int WAVES = 2;             // independent waves (tiles) per workgroup
constexpr int BAND_OUT = 25;         // 20*25 = 500 EXACT -> uniform bands, no last-band y0 shift
constexpr int BANDS_Y = 20;
constexpr int G = 13;                // ring depth == window height
constexpr int NROWS = 37;            // staged rows = 25+12; band19: 475+37 = 512 exact
constexpr int NGROUPS = 2;           // 2 x 13-step groups + 11-step tail = 37
constexpr int TAIL = NROWS - NGROUPS * G;        // 11
constexpr int PAIRS_X = TILES_X / WAVES;        // 2 tile-pairs per band
constexpr int WGS_PER_B = PAIRS_X * BANDS_Y;    // 40 workgroups per batch -> grid 1280 = 5 wg/CU
constexpr int UNITS_PER_B = TILES_X * BANDS_Y;  // 80 partial slots per batch
constexpr int RS = 140;              // LDS row stride: 128 cols + 12 halo (35 lanes x 16B)

// direct global->LDS DMA, 16 B per active lane, dst = uniform base + lane*16
#define GLOAD_LDS16(gp, lp)                                                    \
  __builtin_amdgcn_global_load_lds(                                            \
      (const __attribute__((address_space(1))) unsigned int*)(const void*)(gp),\
      (__attribute__((address_space(3))) unsigned int*)(void*)(lp), 16, 0, 0)

#define WAITV(N) asm volatile("s_waitcnt vmcnt(" #N ")" ::: "memory")
#define WAITL0()  asm volatile("s_waitcnt lgkmcnt(0)" ::: "memory")

// ---------------------------------------------------------------------------
// R18: the last untested lever — a 3rd wave per SIMD.
//  - R17 post-mortem: manual tap pipelining flat (107.9) -> ds_read first-use
//    latency was never the stall. Scheduling lane CLOSED (R12 flat, R14 -1.7,
//    R17 flat). Accounting: VALU issue 15.5us (43%), DS-pipe 12.6us (35%),
//    HBM 8%; both pipes ~40% with dep stalls, TLP pinned at 2 waves/SIMD by
//    (a) VGPR 172 > 170 and (b) grid 1024 = only 8 waves/CU. 4-col/lane dead
//    (ring->260 VGPR), ring-in-LDS dead (33KB/wave), ringless double-h-tree
//    dead (DS-pipe 2x).
//  - This round needs BOTH: VGPR <= 170 AND >= 10 waves/CU of grid.
//    1. g-moments v2f -> scalar accumulators (fold A0.x+A0.y at accumulate):
//       -5 VGPR -> ~167. Cost +5 VALU/step (~2%). NO launch_bounds cap, no
//       attribute (R15 lesson: caps below live-state spill the ring).
//    2. Uniform 20-band geometry (R16's absmax-0-verified ledger) with R14's
//       DYNAMIC group loop (R16's fatal flaw was the static unroll, not the
//       geometry): grid 1280 wg = 5 wg/CU; LDS 29120 -> exactly 5 wg/CU fit.
//    3. R17's tap double-buffer reverted (measured-flat, +28 VGPR).
//  - Fork (m68/m69 open question, VGPR occupancy quantum): fine(~8-granular)
//    -> 3 waves on SIMDs -> dur ~99-103; coarse(halve at 128/256) -> flat
//    ~107-112 (1280-grid tail). PRE-COMMITMENT: flat/worse => structural
//    ceiling established, declare next round.
//  - vmcnt ledger (= R16, verified): prologue 26 (rows 0..12). Group g
//    (t0=13g): WAITV(12) steps 0..6 | WAITL0 burst rows t0+13..19 -> s0..6 |
//    WAITV(14) steps 7..12 | WAITL0 burst rows t0+20..25 -> s7..12 (g=1:
//    rows 33..38 clamp-> 33..36+2dummy). Tail: WAITV(12) steps 26..32
//    (s0..6) | WAITV(4) steps 33..36 (s7..10) | WAITV(0) drain.
// Tripwires: WRITE_SIZE >> 64 or dur > 115 => spill. absmax must stay 0.
// workspace: 2560 * 6 floats = 60 KiB; every slot written.
// ---------------------------------------------------------------------------
__global__ __launch_bounds__(128) void ncc_fused_kernel(
    const float* __restrict__ x1, const float* __restrict__ x2,
    float* __restrict__ part) {
  const int bid = blockIdx.x;
  const int b    = bid / WGS_PER_B;
  const int rem  = bid % WGS_PER_B;
  const int pair = rem % PAIRS_X;
  const int band = rem / PAIRS_X;
  const bool last = (band == BANDS_Y - 1);   // band 19 owns rows 475..511
  const int w    = threadIdx.x >> 6;   // wave id, uniform per wave
  const int lane = threadIdx.x & 63;
  const int tile = pair * WAVES + w;
  const int x0 = tile * TILE_W;
  const int y0 = band * BAND_OUT;      // uniform: 20*25 = 500 exact
  const int c0 = x0 + 2 * lane;
  const bool valid0 = c0 < WP;
  const bool valid1 = (c0 + 1) < WP;

  __shared__ float sa[WAVES][G][RS];   // 2 x 7280 B
  __shared__ float sb[WAVES][G][RS];   // 2 x 7280 B  -> 29120 B total

  const float* r1 = x1 + (size_t)b * NPIX + (size_t)y0 * W + x0;
  const float* r2 = x2 + (size_t)b * NPIX + (size_t)y0 * W + x0;

  // loader: 35 lanes x float4 = 140 floats/row/plane. Tile 3 clamp: lanes
  // 32..34 re-read cols 508..511 into LDS floats 128..139, consumed only by
  // out-cols >= 500 (masked). DMA dst is wave-uniform base + lane*16.
  int qoff = lane * 4;
  { int mx = W - x0 - 4; if (qoff > mx) qoff = mx; }
  const bool loader = lane < 35;

  auto dma_row = [&](int row, int slot) {
    if (loader) {
      GLOAD_LDS16(r1 + (size_t)row * W + qoff, &sa[w][slot][0]);
      GLOAD_LDS16(r2 + (size_t)row * W + qoff, &sb[w][slot][0]);
    }
  };

  // prologue: rows 0..12 into slots 0..12, in row order (26 DMAs in flight)
#pragma unroll
  for (int r = 0; r < G; ++r) dma_row(r, r);

  // vertical ring in registers, v2f across the lane's 2 cols.
  // Zero-init -> fill steps are "slide minus zero": one unified step body.
  v2f rr1[G], rr2[G], rr11[G], rr22[G], rr12[G];
#pragma unroll
  for (int u = 0; u < G; ++u) {
    rr1[u] = (v2f){0.f, 0.f}; rr2[u] = (v2f){0.f, 0.f};
    rr11[u] = (v2f){0.f, 0.f}; rr22[u] = (v2f){0.f, 0.f};
    rr12[u] = (v2f){0.f, 0.f};
  }
  v2f S1 = {0.f, 0.f}, S2 = {0.f, 0.f}, S11 = {0.f, 0.f}, S22 = {0.f, 0.f},
      S12 = {0.f, 0.f};
  // global moments as SCALARS (v2f folded at accumulate): -5 VGPR vs R14
  float g1s = 0.f, g2s = 0.f, g11s = 0.f, g22s = 0.f, g12s = 0.f;
  float acc = 0.f;
  const float inv_n = 1.0f / 169.0f;

  // fence-free step: ds_reads + compute only (no asm, no DMA) — R14 verbatim
  // except scalar g-accumulation.
  auto step = [&](int u, int t) {
    const float* pa = &sa[w][u][2 * lane];
    const float* pb = &sb[w][u][2 * lane];
    v2f A[7], Bv[7];
#pragma unroll
    for (int k = 0; k < 7; ++k) {
      A[k] = *(const v2f*)(pa + 2 * k);   // 8B-aligned ds_read_b64
      Bv[k] = *(const v2f*)(pb + 2 * k);
    }

    // c0 window = floats 0..12; c1 window = floats 1..13 (A[6].y is tap 13)
    v2f q11 = A[0] * A[0], q22 = Bv[0] * Bv[0], q12 = A[0] * Bv[0];
    v2f h1v = A[0], h2v = Bv[0], h11v = q11, h22v = q22, h12v = q12;
#pragma unroll
    for (int k = 1; k < 6; ++k) {
      h1v += A[k];
      h2v += Bv[k];
      h11v += A[k] * A[k];
      h22v += Bv[k] * Bv[k];
      h12v += A[k] * Bv[k];
    }
    float a12 = A[6].x, b12 = Bv[6].x, a13 = A[6].y, b13 = Bv[6].y;
    float h1_0 = h1v.x + h1v.y + a12;
    float h2_0 = h2v.x + h2v.y + b12;
    float h11_0 = fmaf(a12, a12, h11v.x + h11v.y);
    float h22_0 = fmaf(b12, b12, h22v.x + h22v.y);
    float h12_0 = fmaf(a12, b12, h12v.x + h12v.y);
    // incremental shift for c1
    v2f h1 = {h1_0, h1_0 - A[0].x + a13};
    v2f h2 = {h2_0, h2_0 - Bv[0].x + b13};
    v2f h11 = {h11_0, fmaf(a13, a13, h11_0 - q11.x)};
    v2f h22 = {h22_0, fmaf(b13, b13, h22_0 - q22.x)};
    v2f h12 = {h12_0, fmaf(a13, b13, h12_0 - q12.x)};

    // global moments: bands 0..18 own t<25; band 19 owns all 37 staged rows.
    // Scalar accumulators (fold the col pair here, not at the end).
    bool owned = (t < BAND_OUT) || last;
    if (owned) {
      g1s += A[0].x + A[0].y;
      g2s += Bv[0].x + Bv[0].y;
      g11s += q11.x + q11.y;
      g22s += q22.x + q22.y;
      g12s += q12.x + q12.y;
    }

    // vertical sliding sums via register ring (rr starts at 0 -> fill==slide)
    S1 += h1 - rr1[u]; S2 += h2 - rr2[u];
    S11 += h11 - rr11[u]; S22 += h22 - rr22[u]; S12 += h12 - rr12[u];
    rr1[u] = h1; rr2[u] = h2; rr11[u] = h11; rr22[u] = h22; rr12[u] = h12;

    // emit output row y0 + t - 12 (uniform: every band emits t in [12,37))
    if (t >= 12) {
      v2f m1 = S1 * inv_n, m2 = S2 * inv_n;
      v2f vv1 = S11 * inv_n - m1 * m1 + EPS;
      v2f vv2 = S22 * inv_n - m2 * m2 + EPS;
      v2f cross = S12 - (S1 * inv_n) * S2;
      v2f den = vv1 * vv2;
      float cc0 = cross.x * rsqrtf(den.x);
      float cc1 = cross.y * rsqrtf(den.y);
      acc += (valid0 ? cc0 : 0.f) + (valid1 ? cc1 : 0.f);
    }
  };

  // 2 groups of 13 steps; DYNAMIC loop (backedge closes live ranges — R16
  // lesson); 13-step body unrolled inside (static slot indices, rule #20).
#pragma clang loop unroll(disable)
  for (int g = 0; g < NGROUPS; ++g) {
    const int t0 = g * G;
    // ---- phase A: rows t0..t0+6 landed (12 newer = previous end-burst) ----
    WAITV(12);
#pragma unroll
    for (int u = 0; u <= 6; ++u) step(u, t0 + u);
    WAITL0();                      // steps 0..6 tap reads retired
#pragma unroll
    for (int j = 0; j <= 6; ++j) { // mid-burst: rows t0+13+j -> slot j (14)
      int nrow = t0 + G + j;
      if (nrow > NROWS - 1) nrow = NROWS - 1;
      dma_row(nrow, j);
    }
    // ---- phase B: rows t0+7..t0+12 landed (14 newer = mid-burst above) ----
    WAITV(14);
#pragma unroll
    for (int u = 7; u <= 12; ++u) step(u, t0 + u);
    WAITL0();                      // steps 7..12 tap reads retired
#pragma unroll
    for (int j = 7; j <= 12; ++j) { // end-burst: rows t0+13+j -> slot j (12)
      int nrow = t0 + G + j;       // g=1: 33..38 -> clamp 33..36 + 2 dummies
      if (nrow > NROWS - 1) nrow = NROWS - 1;
      dma_row(nrow, j);
    }
  }

  // tail: steps 26..36 (11 steps). Rows 26..32 from g1 mid-burst (slots
  // 0..6), rows 33..36 from g1 end-burst (slots 7..10).
  WAITV(12);
#pragma unroll
  for (int u = 0; u <= 6; ++u) step(u, 26 + u);       // t = 26..32
  WAITV(4);                         // rows 33..36 landed (4 newer = dummies)
#pragma unroll
  for (int u = 7; u <= 10; ++u) step(u, 26 + u);      // t = 33..36

  // drain dummy DMAs before this block's LDS can be reallocated
  asm volatile("s_waitcnt vmcnt(0)" ::: "memory");

  // wave-reduce 6 scalars, lane 0 of each wave writes its slot
  float v0 = acc;
  float w1 = g1s, w2 = g2s, w3 = g11s, w4 = g22s, w5 = g12s;
#pragma unroll
  for (int off = 32; off > 0; off >>= 1) {
    v0 += __shfl_down(v0, off, 64);
    w1 += __shfl_down(w1, off, 64);
    w2 += __shfl_down(w2, off, 64);
    w3 += __shfl_down(w3, off, 64);
    w4 += __shfl_down(w4, off, 64);
    w5 += __shfl_down(w5, off, 64);
  }
  if (lane == 0) {
    float* o = part + (size_t)(bid * WAVES + w) * 6;
    o[0] = v0; o[1] = w1; o[2] = w2; o[3] = w3; o[4] = w4; o[5] = w5;
  }
}

// ---------------------------------------------------------------------------
// Reduce per-unit partials; one block per batch (80 units).
// out[b] = 0.5*global_ncc + 0.5*patch_sum/(HP*WP*169)
// ---------------------------------------------------------------------------
__global__ __launch_bounds__(64) void final_kernel(
    const float* __restrict__ part, float* __restrict__ out) {
  int b = blockIdx.x;
  int tid = threadIdx.x;
  float s[6] = {0.f, 0.f, 0.f, 0.f, 0.f, 0.f};
  for (int i = tid; i < UNITS_PER_B; i += 64) {
    const float* p = part + (size_t)(b * UNITS_PER_B + i) * 6;
#pragma unroll
    for (int k = 0; k < 6; ++k) s[k] += p[k];
  }
#pragma unroll
  for (int off = 32; off > 0; off >>= 1) {
#pragma unroll
    for (int k = 0; k < 6; ++k) s[k] += __shfl_down(s[k], off, 64);
  }
  if (tid == 0) {
    float Nf = (float)NPIX;
    float m1 = s[1] / Nf;
    float m2 = s[2] / Nf;
    float v1 = fmaf(-m1, m1, s[3] / Nf);
    float v2 = fmaf(-m2, m2, s[4] / Nf);
    float cross = fmaf(-Nf * m1, m2, s[5]);
    float g = cross * rsqrtf((v1 + EPS) * (v2 + EPS)) / Nf;
    float patch = s[0] / ((float)HP * (float)WP * 169.0f);
    out[b] = 0.5f * g + 0.5f * patch;
  }
}

extern "C" void kernel_launch(void* const* d_in, const int* in_sizes, int n_in,
                              void* d_out, int out_size, void* d_ws, size_t ws_size,
                              hipStream_t stream) {
  const float* x1 = (const float*)d_in[0];
  const float* x2 = (const float*)d_in[1];
  float* out = (float*)d_out;
  float* part = (float*)d_ws;   // 2560 * 6 floats = 60 KiB; every slot written

  ncc_fused_kernel<<<B * WGS_PER_B, WAVES * 64, 0, stream>>>(x1, x2, part);
  final_kernel<<<B, 64, 0, stream>>>(part, out);
}

// Round 13
// 106.278 us; speedup vs baseline: 1.2028x; 1.2028x over previous
//
#include <hip/hip_runtime.h>

#define EPS 1e-5f

typedef float v2f __attribute__((ext_vector_type(2)));

constexpr int B = 32;
constexpr int H = 512;
constexpr int W = 512;
constexpr int NPIX = H * W;          // 262144
constexpr int P = 13;
constexpr int HP = H - P + 1;        // 500
constexpr int WP = W - P + 1;        // 500
constexpr int TILE_W = 128;          // output cols per wave, 2 per lane
constexpr int TILES_X = 4;
constexpr int WAVES = 2;             // independent waves (tiles) per workgroup
constexpr int BAND_OUT = 33;         // output rows per band
constexpr int BANDS_Y = 16;          // 15*33=495<500<=16*33; last band y0=467
constexpr int G = 13;                // ring depth == window height
constexpr int NROWS = 45;            // staged rows per band = 33+12; 467+45=512 -> no clamp
constexpr int NGROUPS = 3;           // 3 x 13-step groups + 6-step tail = 45
constexpr int TAIL = NROWS - NGROUPS * G;        // 6
constexpr int ITER_LAST_OWN = 28;    // band 15 owns input rows 495..511 -> t >= 28
constexpr int ITER_LAST_EMIT = 40;   // band 15 emits out rows 495..499 -> t >= 40
constexpr int PAIRS_X = TILES_X / WAVES;        // 2 tile-pairs per band
constexpr int WGS_PER_B = PAIRS_X * BANDS_Y;    // 32 workgroups per batch
constexpr int UNITS_PER_B = TILES_X * BANDS_Y;  // 64 partial slots per batch
constexpr int RS = 140;              // LDS row stride: 128 cols + 12 halo (35 lanes x 16B)

// direct global->LDS DMA, 16 B per active lane, dst = uniform base + lane*16
#define GLOAD_LDS16(gp, lp)                                                    \
  __builtin_amdgcn_global_load_lds(                                            \
      (const __attribute__((address_space(1))) unsigned int*)(const void*)(gp),\
      (__attribute__((address_space(3))) unsigned int*)(void*)(lp), 16, 0, 0)

#define WAITV(N) asm volatile("s_waitcnt vmcnt(" #N ")" ::: "memory")
#define WAITL0()  asm volatile("s_waitcnt lgkmcnt(0)" ::: "memory")

// ---------------------------------------------------------------------------
// R19 = R14 restored verbatim (session best, 107.15us verified @ R8).
//  - R18 post-mortem: third and final occupancy-lever failure. g-scalar +
//    11-step tail -> VGPR 256 + 10MB spills (ncc ~54us, dur 127.8). Record
//    on reaching <=170 VGPR: natural alloc 172-256 (R14/R18); launch_bounds
//    cap -> 84 + full ring spill (R15); static unroll -> 256 + spill (R16).
//    NO PATH to 3 waves/SIMD with the 130-VGPR ring — and the ring IS the
//    O(P)->O(1) sliding-sum that makes the kernel fast.
//  - Structural ceiling (per R18 pre-commitment): ncc ~36-38us vs pipe
//    floors VALU 15.5us (43% busy) + DS 12.6us (~35%) at a hard 2
//    waves/SIMD; scheduling variants (R12/R14/R17) all <=2%; geometry
//    (R11/R18), dispatch economy (R10), instruction pruning (R16) all
//    falsified or exhausted. Of dur 107: ~41us harness workspace-poison
//    fill + ~30us launch overhead/final + ~36us ncc.
//  - Structure: 2 waves/wg x 128-col tiles, no barriers (disjoint LDS,
//    per-wave vmcnt); 13-slot LDS ring; coarse per-half-group fences:
//    WAITV(12) 7 steps | WAITL0 burst 7 rows | WAITV(14) 6 steps | WAITL0
//    burst 6 rows; tail WAITV(12)+6 steps; final drain. Grid 1024 = 4/CU.
// ---------------------------------------------------------------------------
__global__ __launch_bounds__(128) void ncc_fused_kernel(
    const float* __restrict__ x1, const float* __restrict__ x2,
    float* __restrict__ part) {
  const int bid = blockIdx.x;
  const int b    = bid / WGS_PER_B;
  const int rem  = bid % WGS_PER_B;
  const int pair = rem % PAIRS_X;
  const int band = rem / PAIRS_X;
  const bool last = (band == BANDS_Y - 1);
  const int w    = threadIdx.x >> 6;   // wave id, uniform per wave
  const int lane = threadIdx.x & 63;
  const int tile = pair * WAVES + w;
  const int x0 = tile * TILE_W;
  const int y0 = last ? (HP - BAND_OUT) : band * BAND_OUT;  // 467 for last band
  const int c0 = x0 + 2 * lane;
  const bool valid0 = c0 < WP;
  const bool valid1 = (c0 + 1) < WP;

  __shared__ float sa[WAVES][G][RS];   // 2 x 7280 B
  __shared__ float sb[WAVES][G][RS];   // 2 x 7280 B  -> 29120 B total

  const float* r1 = x1 + (size_t)b * NPIX + (size_t)y0 * W + x0;
  const float* r2 = x2 + (size_t)b * NPIX + (size_t)y0 * W + x0;

  // loader: 35 lanes x float4 = 140 floats/row/plane. Tile 3 clamp: lanes
  // 32..34 re-read cols 508..511 into LDS floats 128..139, consumed only by
  // out-cols >= 500 (masked). DMA dst is wave-uniform base + lane*16.
  int qoff = lane * 4;
  { int mx = W - x0 - 4; if (qoff > mx) qoff = mx; }
  const bool loader = lane < 35;

  auto dma_row = [&](int row, int slot) {
    if (loader) {
      GLOAD_LDS16(r1 + (size_t)row * W + qoff, &sa[w][slot][0]);
      GLOAD_LDS16(r2 + (size_t)row * W + qoff, &sb[w][slot][0]);
    }
  };

  // prologue: rows 0..12 into slots 0..12, in row order (26 DMAs in flight)
#pragma unroll
  for (int r = 0; r < G; ++r) dma_row(r, r);

  // vertical ring in registers, v2f across the lane's 2 cols.
  // Zero-init -> fill steps are "slide minus zero": one unified step body.
  v2f rr1[G], rr2[G], rr11[G], rr22[G], rr12[G];
#pragma unroll
  for (int u = 0; u < G; ++u) {
    rr1[u] = (v2f){0.f, 0.f}; rr2[u] = (v2f){0.f, 0.f};
    rr11[u] = (v2f){0.f, 0.f}; rr22[u] = (v2f){0.f, 0.f};
    rr12[u] = (v2f){0.f, 0.f};
  }
  v2f S1 = {0.f, 0.f}, S2 = {0.f, 0.f}, S11 = {0.f, 0.f}, S22 = {0.f, 0.f},
      S12 = {0.f, 0.f};
  v2f g1 = {0.f, 0.f}, g2 = {0.f, 0.f}, g11 = {0.f, 0.f}, g22 = {0.f, 0.f},
      g12 = {0.f, 0.f};
  float acc = 0.f;
  const float inv_n = 1.0f / 169.0f;

  // fence-free step: ds_reads + compute only (no asm, no DMA)
  auto step = [&](int u, int t) {
    const float* pa = &sa[w][u][2 * lane];
    const float* pb = &sb[w][u][2 * lane];
    v2f A[7], Bv[7];
#pragma unroll
    for (int k = 0; k < 7; ++k) {
      A[k] = *(const v2f*)(pa + 2 * k);   // 8B-aligned ds_read_b64
      Bv[k] = *(const v2f*)(pb + 2 * k);
    }

    // c0 window = floats 0..12; c1 window = floats 1..13 (A[6].y is tap 13)
    v2f q11 = A[0] * A[0], q22 = Bv[0] * Bv[0], q12 = A[0] * Bv[0];
    v2f h1v = A[0], h2v = Bv[0], h11v = q11, h22v = q22, h12v = q12;
#pragma unroll
    for (int k = 1; k < 6; ++k) {
      h1v += A[k];
      h2v += Bv[k];
      h11v += A[k] * A[k];
      h22v += Bv[k] * Bv[k];
      h12v += A[k] * Bv[k];
    }
    float a12 = A[6].x, b12 = Bv[6].x, a13 = A[6].y, b13 = Bv[6].y;
    float h1_0 = h1v.x + h1v.y + a12;
    float h2_0 = h2v.x + h2v.y + b12;
    float h11_0 = fmaf(a12, a12, h11v.x + h11v.y);
    float h22_0 = fmaf(b12, b12, h22v.x + h22v.y);
    float h12_0 = fmaf(a12, b12, h12v.x + h12v.y);
    // incremental shift for c1
    v2f h1 = {h1_0, h1_0 - A[0].x + a13};
    v2f h2 = {h2_0, h2_0 - Bv[0].x + b13};
    v2f h11 = {h11_0, fmaf(a13, a13, h11_0 - q11.x)};
    v2f h22 = {h22_0, fmaf(b13, b13, h22_0 - q22.x)};
    v2f h12 = {h12_0, fmaf(a13, b13, h12_0 - q12.x)};

    // global moments: own cols (c0,c1) = A[0]/Bv[0] as v2f; squares reused
    bool owned = last ? (t >= ITER_LAST_OWN) : (t < BAND_OUT);
    if (owned) {
      g1 += A[0]; g2 += Bv[0]; g11 += q11; g22 += q22; g12 += q12;
    }

    // vertical sliding sums via register ring (rr starts at 0 -> fill==slide)
    S1 += h1 - rr1[u]; S2 += h2 - rr2[u];
    S11 += h11 - rr11[u]; S22 += h22 - rr22[u]; S12 += h12 - rr12[u];
    rr1[u] = h1; rr2[u] = h2; rr11[u] = h11; rr22[u] = h22; rr12[u] = h12;

    // emit output row y0 + t - 12 (band 15 suppresses rows < 495)
    bool do_out = (t >= 12) && (!last || t >= ITER_LAST_EMIT);
    if (do_out) {
      v2f m1 = S1 * inv_n, m2 = S2 * inv_n;
      v2f vv1 = S11 * inv_n - m1 * m1 + EPS;
      v2f vv2 = S22 * inv_n - m2 * m2 + EPS;
      v2f cross = S12 - (S1 * inv_n) * S2;
      v2f den = vv1 * vv2;
      float cc0 = cross.x * rsqrtf(den.x);
      float cc1 = cross.y * rsqrtf(den.y);
      acc += (valid0 ? cc0 : 0.f) + (valid1 ? cc1 : 0.f);
    }
  };

  // 3 groups of 13 steps; slot indices static (13-unrolled bodies, rule #20)
#pragma clang loop unroll(disable)
  for (int g = 0; g < NGROUPS; ++g) {
    const int t0 = g * G;
    // ---- phase A: rows t0..t0+6 landed (12 newer = previous end-burst) ----
    WAITV(12);
#pragma unroll
    for (int u = 0; u <= 6; ++u) step(u, t0 + u);
    WAITL0();                      // steps 0..6 tap reads retired
#pragma unroll
    for (int j = 0; j <= 6; ++j) { // mid-burst: rows t0+13+j -> slot j (14)
      int nrow = t0 + G + j;
      if (nrow > NROWS - 1) nrow = NROWS - 1;   // group 2: dummies, unread
      dma_row(nrow, j);
    }
    // ---- phase B: rows t0+7..t0+12 landed (14 newer = mid-burst above) ----
    WAITV(14);
#pragma unroll
    for (int u = 7; u <= 12; ++u) step(u, t0 + u);
    WAITL0();                      // steps 7..12 tap reads retired
#pragma unroll
    for (int j = 7; j <= 12; ++j) { // end-burst: rows t0+13+j -> slot j (12)
      int nrow = t0 + G + j;
      if (nrow > NROWS - 1) nrow = NROWS - 1;
      dma_row(nrow, j);
    }
  }

  // tail: steps 39..44 on slots 0..5 (rows 39..44, from group-2 mid-burst)
  WAITV(12);
#pragma unroll
  for (int u = 0; u < TAIL; ++u) step(u, NGROUPS * G + u);

  // drain all DMAs (incl. dummies) before this block's LDS can be reallocated
  asm volatile("s_waitcnt vmcnt(0)" ::: "memory");

  // fold v2f col-pairs, wave-reduce 6 scalars, lane 0 of each wave writes slot
  float v0 = acc;
  float w1 = g1.x + g1.y, w2 = g2.x + g2.y;
  float w3 = g11.x + g11.y, w4 = g22.x + g22.y, w5 = g12.x + g12.y;
#pragma unroll
  for (int off = 32; off > 0; off >>= 1) {
    v0 += __shfl_down(v0, off, 64);
    w1 += __shfl_down(w1, off, 64);
    w2 += __shfl_down(w2, off, 64);
    w3 += __shfl_down(w3, off, 64);
    w4 += __shfl_down(w4, off, 64);
    w5 += __shfl_down(w5, off, 64);
  }
  if (lane == 0) {
    // uid = b*64 + rem*2 + w : contiguous per batch
    float* o = part + (size_t)(bid * WAVES + w) * 6;
    o[0] = v0; o[1] = w1; o[2] = w2; o[3] = w3; o[4] = w4; o[5] = w5;
  }
}

// ---------------------------------------------------------------------------
// Reduce per-unit partials; one block per batch (64 units -> one per thread).
// out[b] = 0.5*global_ncc + 0.5*patch_sum/(HP*WP*169)
// ---------------------------------------------------------------------------
__global__ __launch_bounds__(64) void final_kernel(
    const float* __restrict__ part, float* __restrict__ out) {
  int b = blockIdx.x;
  int tid = threadIdx.x;
  float s[6] = {0.f, 0.f, 0.f, 0.f, 0.f, 0.f};
  for (int i = tid; i < UNITS_PER_B; i += 64) {
    const float* p = part + (size_t)(b * UNITS_PER_B + i) * 6;
#pragma unroll
    for (int k = 0; k < 6; ++k) s[k] += p[k];
  }
#pragma unroll
  for (int off = 32; off > 0; off >>= 1) {
#pragma unroll
    for (int k = 0; k < 6; ++k) s[k] += __shfl_down(s[k], off, 64);
  }
  if (tid == 0) {
    float Nf = (float)NPIX;
    float m1 = s[1] / Nf;
    float m2 = s[2] / Nf;
    float v1 = fmaf(-m1, m1, s[3] / Nf);
    float v2 = fmaf(-m2, m2, s[4] / Nf);
    float cross = fmaf(-Nf * m1, m2, s[5]);
    float g = cross * rsqrtf((v1 + EPS) * (v2 + EPS)) / Nf;
    float patch = s[0] / ((float)HP * (float)WP * 169.0f);
    out[b] = 0.5f * g + 0.5f * patch;
  }
}

extern "C" void kernel_launch(void* const* d_in, const int* in_sizes, int n_in,
                              void* d_out, int out_size, void* d_ws, size_t ws_size,
                              hipStream_t stream) {
  const float* x1 = (const float*)d_in[0];
  const float* x2 = (const float*)d_in[1];
  float* out = (float*)d_out;
  float* part = (float*)d_ws;   // 2048 * 6 floats = 48 KiB; every slot written

  ncc_fused_kernel<<<B * WGS_PER_B, WAVES * 64, 0, stream>>>(x1, x2, part);
  final_kernel<<<B, 64, 0, stream>>>(part, out);
}